// Round 10
// baseline (591.669 us; speedup 1.0000x reference)
//
#include <hip/hip_runtime.h>

// out[m,n] = sum_k x[m,k] * (qw[k,n]*scale[n]) + bias[n]
// M=8192, K=1024, N=4096 fp32. Scale factors out of K-sum -> bf16 MFMA GEMM.
//   pass1 (merged): x fp32 -> bf16 [M][K]  and  qw [K][N] fp32 -> wT [N][K] bf16
//   pass2: 256x256 GEMM, BK=32, 64 KiB LDS -> 2 blocks/CU (512 blocks = 1 round;
//          sibling block hides barrier/epilogue stalls). 8-phase discipline kept:
//          per phase [ds_read frags; issue staging; barrier; lgkmcnt(0); setprio;
//          8 MFMA; barrier]. Conflict-free 2-bit swizzle for 64B rows (validated
//          family: R7 measured BANK_CONFLICT=0 with the 128B-row analog).

#define Mdim 8192
#define Ndim 4096
#define Kdim 1024
#define NT2 32  // Kdim/32 K-tiles

typedef __attribute__((ext_vector_type(8))) short short8;
typedef __attribute__((ext_vector_type(4))) float floatx4;
typedef __attribute__((ext_vector_type(4))) unsigned short ushort4v;
typedef __attribute__((ext_vector_type(8))) unsigned short ushort8v;

__device__ inline unsigned short f2bf(float f) {
    unsigned int u = __builtin_bit_cast(unsigned int, f);
    u = (u + 0x7fffu + ((u >> 16) & 1u)) >> 16;
    return (unsigned short)u;
}

#define GLOAD_LDS16(gsrc, ldst)                                                             \
    __builtin_amdgcn_global_load_lds((const __attribute__((address_space(1))) void*)(gsrc), \
                                     (__attribute__((address_space(3))) void*)(ldst), 16, 0, 0)

// ---------------- pass 1: both conversions in one launch ----------------
__global__ __launch_bounds__(256) void cvt_kernel(const float* __restrict__ x,
                                                  const float* __restrict__ qw,
                                                  unsigned short* __restrict__ xb,
                                                  unsigned short* __restrict__ wT) {
    __shared__ unsigned short tile[64][66];
    if (blockIdx.x < 1024) {
        int bn = blockIdx.x & 63;
        int bk = blockIdx.x >> 6;
        int tx = threadIdx.x & 15;
        int ty = threadIdx.x >> 4;
        const float* src = qw + (size_t)(bk * 64) * Ndim + bn * 64 + tx * 4;
#pragma unroll
        for (int i = 0; i < 4; ++i) {
            int r = ty + i * 16;
            float4 v = *(const float4*)(src + (size_t)r * Ndim);
            tile[r][tx * 4 + 0] = f2bf(v.x);
            tile[r][tx * 4 + 1] = f2bf(v.y);
            tile[r][tx * 4 + 2] = f2bf(v.z);
            tile[r][tx * 4 + 3] = f2bf(v.w);
        }
        __syncthreads();
        unsigned short* dst = wT + (size_t)(bn * 64) * Kdim + bk * 64 + tx * 4;
#pragma unroll
        for (int i = 0; i < 4; ++i) {
            int r = ty + i * 16;
            ushort4v o;
            o[0] = tile[tx * 4 + 0][r];
            o[1] = tile[tx * 4 + 1][r];
            o[2] = tile[tx * 4 + 2][r];
            o[3] = tile[tx * 4 + 3][r];
            *(ushort4v*)(dst + (size_t)r * Kdim) = o;
        }
    } else {
        int i = (blockIdx.x - 1024) * 256 + threadIdx.x;  // exactly M*K/8 threads
        const float4* p = (const float4*)x + (size_t)i * 2;
        float4 a = p[0], b = p[1];
        ushort8v o;
        o[0] = f2bf(a.x); o[1] = f2bf(a.y); o[2] = f2bf(a.z); o[3] = f2bf(a.w);
        o[4] = f2bf(b.x); o[5] = f2bf(b.y); o[6] = f2bf(b.z); o[7] = f2bf(b.w);
        *((ushort8v*)xb + i) = o;
    }
}

// ---------------- pass 2: 256x256 GEMM, BK=32, 2 blocks/CU ----------------
// LDS 64 KiB: [dbuf 32768][A 16384 | B 16384]; row r (0..255) at byte r*64 in its
// tile; quarter q (128 rows) = 8 KiB = 1 global_load_lds16 per thread.
// Swizzle (64B rows): phys = L ^ (((L>>7)&3)<<4)  (row bits 1-2 -> byte bits 4-5).
// Quarter-wave covers all 8 bank-groups exactly 2x => conflict-free.
// Read side: ca = (lq ^ ((la>>1)&3))<<4 (per-lane constant; m/ni/wr/wc terms
// don't touch row bits 1-2).
__global__ __launch_bounds__(512, 4) void gemm_kernel(const unsigned short* __restrict__ xb,
                                                      const unsigned short* __restrict__ wT,
                                                      const float* __restrict__ scales,
                                                      const float* __restrict__ bias,
                                                      float* __restrict__ out) {
    extern __shared__ char ldsc[];

    // XCD-bijective swizzle: nwg = 512, 512 % 8 == 0
    int bid = blockIdx.x;
    int swz = (bid & 7) * 64 + (bid >> 3);
    int tile_n = swz & 15;   // fast: neighbors share A panel in L2
    int tile_m = swz >> 4;

    int tid = threadIdx.x;
    int wid = tid >> 6, lane = tid & 63;
    int wr = wid >> 2, wc = wid & 3;     // wave -> (128 rows, 64 cols) sub-tile
    int la = lane & 15, lq = lane >> 4;

    // ---- staging: dest byte d=tid*16 (linear); source = inverse-swizzled ----
    int d = tid * 16;
    int L = d ^ (((d >> 7) & 3) << 4);                 // involution
    int g_off = (L >> 6) * Kdim + ((L & 63) >> 1);     // row-in-quarter, col-short
    const unsigned short* aTile = xb + (size_t)tile_m * 256 * Kdim;
    const unsigned short* bTile = wT + (size_t)tile_n * 256 * Kdim;

    auto ISSUE = [&](int t, int op, int q) {   // one quarter-tile = 1 load/thread
        if (t >= NT2) return;
        const unsigned short* g =
            (op ? bTile : aTile) + (size_t)q * 128 * Kdim + t * 32 + g_off;
        GLOAD_LDS16(g, ldsc + (t & 1) * 32768 + op * 16384 + q * 8192 + d);
    };

    // ---- ds_read addressing ----
    int ca = (lq ^ ((la >> 1) & 3)) << 4;    // swizzled k-slot byte
    int arow = (wr * 128 + la) * 64;         // + m*1024
    int brow = wc * 4096 + la * 64;          // + ni*1024

    floatx4 acc[8][4] = {};
    short8 af[2], bfr[4];

#define RD_A2(P)                                                                       \
    af[0] = *(const short8*)(abase + arow + (P) * 2048 + ca);                          \
    af[1] = *(const short8*)(abase + arow + (P) * 2048 + 1024 + ca);
#define RD_B()                                                                         \
    _Pragma("unroll") for (int ni = 0; ni < 4; ++ni)                                   \
        bfr[ni] = *(const short8*)(bbase + brow + ni * 1024 + ca);
#define MM(P)                                                                          \
    _Pragma("unroll") for (int m2 = 0; m2 < 2; ++m2)                                   \
    _Pragma("unroll") for (int ni = 0; ni < 4; ++ni)                                   \
        acc[(P) * 2 + m2][ni] = __builtin_amdgcn_mfma_f32_16x16x32_bf16(               \
            af[m2], bfr[ni], acc[(P) * 2 + m2][ni], 0, 0, 0);
#define SYNC_PRE                                            \
    __builtin_amdgcn_s_barrier();                           \
    asm volatile("s_waitcnt lgkmcnt(0)" ::: "memory");      \
    __builtin_amdgcn_s_setprio(1);
#define SYNC_POST                                           \
    __builtin_amdgcn_s_setprio(0);                          \
    __builtin_amdgcn_s_barrier();

#define TILE(t, BUF)                                                                   \
    {                                                                                  \
        const char* abase = ldsc + (BUF) * 32768;                                      \
        const char* bbase = ldsc + (BUF) * 32768 + 16384;                              \
        /* ph0: B + A frags 0,1; issue next tile's B */                                \
        RD_B(); RD_A2(0);                                                              \
        ISSUE((t) + 1, 1, 0); ISSUE((t) + 1, 1, 1);                                    \
        SYNC_PRE; MM(0); SYNC_POST;                                                    \
        /* ph1: A frags 2,3; issue next tile's A */                                    \
        RD_A2(1);                                                                      \
        ISSUE((t) + 1, 0, 0); ISSUE((t) + 1, 0, 1);                                    \
        SYNC_PRE; MM(1); SYNC_POST;                                                    \
        /* ph2: A frags 4,5 */                                                         \
        RD_A2(2);                                                                      \
        SYNC_PRE; MM(2); SYNC_POST;                                                    \
        /* ph3: A frags 6,7; tile-end staging drain */                                 \
        RD_A2(3);                                                                      \
        SYNC_PRE; MM(3);                                                               \
        __builtin_amdgcn_s_setprio(0);                                                 \
        asm volatile("s_waitcnt vmcnt(0)" ::: "memory");                               \
        __builtin_amdgcn_s_barrier();                                                  \
    }

    // ---- prologue: stage tile0; drain; loop ----
    ISSUE(0, 1, 0); ISSUE(0, 1, 1); ISSUE(0, 0, 0); ISSUE(0, 0, 1);
    asm volatile("s_waitcnt vmcnt(0)" ::: "memory");
    __builtin_amdgcn_s_barrier();

#pragma unroll 1
    for (int t = 0; t < NT2; t += 2) {
        TILE(t, 0);
        TILE(t + 1, 1);
    }

    // ---- epilogue: out = acc * scale[n] + bias[n] ----
    size_t m_base = (size_t)tile_m * 256 + wr * 128;
    int n_base = tile_n * 256 + wc * 64;
#pragma unroll
    for (int ni = 0; ni < 4; ++ni) {
        int col = n_base + ni * 16 + la;
        float s = scales[col], bb2 = bias[col];
#pragma unroll
        for (int mi = 0; mi < 8; ++mi) {
            size_t row0 = m_base + mi * 16 + lq * 4;
#pragma unroll
            for (int v = 0; v < 4; ++v)
                out[(row0 + v) * Ndim + col] = acc[mi][ni][v] * s + bb2;
        }
    }
#undef RD_A2
#undef RD_B
#undef MM
#undef SYNC_PRE
#undef SYNC_POST
#undef TILE
}

// ---------------- fallback ----------------
__global__ __launch_bounds__(256) void fallback_kernel(const float* __restrict__ x,
                                                       const float* __restrict__ qw,
                                                       const float* __restrict__ scales,
                                                       const float* __restrict__ bias,
                                                       float* __restrict__ out) {
    size_t idx = (size_t)blockIdx.x * 256 + threadIdx.x;
    size_t m = idx / Ndim, n = idx % Ndim;
    float sum = 0.f;
    for (int k = 0; k < Kdim; ++k) sum += x[m * Kdim + k] * qw[(size_t)k * Ndim + n];
    out[idx] = sum * scales[n] + bias[n];
}

extern "C" void kernel_launch(void* const* d_in, const int* in_sizes, int n_in,
                              void* d_out, int out_size, void* d_ws, size_t ws_size,
                              hipStream_t stream) {
    const float* x = (const float*)d_in[0];
    const float* qw = (const float*)d_in[1];
    const float* scales = (const float*)d_in[2];
    const float* bias = (const float*)d_in[3];
    float* out = (float*)d_out;

    size_t need = (size_t)Mdim * Kdim * 2 + (size_t)Ndim * Kdim * 2;  // 24 MB
    if (ws_size < need) {
        fallback_kernel<<<(Mdim * (size_t)Ndim) / 256, 256, 0, stream>>>(x, qw, scales, bias, out);
        return;
    }

    unsigned short* xb = (unsigned short*)d_ws;
    unsigned short* wT = xb + (size_t)Mdim * Kdim;

    (void)hipFuncSetAttribute((const void*)gemm_kernel,
                              hipFuncAttributeMaxDynamicSharedMemorySize, 65536);

    cvt_kernel<<<1024 + Mdim * Kdim / (8 * 256), 256, 0, stream>>>(x, qw, xb, wT);
    gemm_kernel<<<(Mdim / 256) * (Ndim / 256), 512, 65536, stream>>>(xb, wT, scales, bias, out);
}

// Round 11
// 230.351 us; speedup vs baseline: 2.5686x; 2.5686x over previous
//
#include <hip/hip_runtime.h>

// out[m,n] = sum_k x[m,k] * (qw[k,n]*scale[n]) + bias[n]
// M=8192, K=1024, N=4096 fp32. Scale factors out of K-sum -> bf16 MFMA GEMM.
//   pass1 (merged): x fp32 -> bf16 [M][K]  and  qw [K][N] fp32 -> wT [N][K] bf16
//   pass2: 256x256 GEMM, BK=64, 8 waves, 1 barrier + 1 vmcnt(0) PER K-TILE.
//          Whole-tile fragments in registers (B persistent, A quarters ping-pong
//          refilled under MFMA); compiler emits counted lgkm waits -> LDS reads
//          overlap MFMA. Conflict-free 3-bit swizzle (R7/R9: BANK_CONFLICT=0).
//          R10 lesson: launch_bounds min-waves stays 2 (256-reg cap; 4 spilled).

#define Mdim 8192
#define Ndim 4096
#define Kdim 1024
#define NT 16  // Kdim/64 K-tiles

typedef __attribute__((ext_vector_type(8))) short short8;
typedef __attribute__((ext_vector_type(4))) float floatx4;
typedef __attribute__((ext_vector_type(4))) unsigned short ushort4v;
typedef __attribute__((ext_vector_type(8))) unsigned short ushort8v;

__device__ inline unsigned short f2bf(float f) {
    unsigned int u = __builtin_bit_cast(unsigned int, f);
    u = (u + 0x7fffu + ((u >> 16) & 1u)) >> 16;
    return (unsigned short)u;
}

#define GLOAD_LDS16(gsrc, ldst)                                                             \
    __builtin_amdgcn_global_load_lds((const __attribute__((address_space(1))) void*)(gsrc), \
                                     (__attribute__((address_space(3))) void*)(ldst), 16, 0, 0)

// ---------------- pass 1: both conversions in one launch ----------------
__global__ __launch_bounds__(256) void cvt_kernel(const float* __restrict__ x,
                                                  const float* __restrict__ qw,
                                                  unsigned short* __restrict__ xb,
                                                  unsigned short* __restrict__ wT) {
    __shared__ unsigned short tile[64][66];
    if (blockIdx.x < 1024) {
        int bn = blockIdx.x & 63;
        int bk = blockIdx.x >> 6;
        int tx = threadIdx.x & 15;
        int ty = threadIdx.x >> 4;
        const float* src = qw + (size_t)(bk * 64) * Ndim + bn * 64 + tx * 4;
#pragma unroll
        for (int i = 0; i < 4; ++i) {
            int r = ty + i * 16;
            float4 v = *(const float4*)(src + (size_t)r * Ndim);
            tile[r][tx * 4 + 0] = f2bf(v.x);
            tile[r][tx * 4 + 1] = f2bf(v.y);
            tile[r][tx * 4 + 2] = f2bf(v.z);
            tile[r][tx * 4 + 3] = f2bf(v.w);
        }
        __syncthreads();
        unsigned short* dst = wT + (size_t)(bn * 64) * Kdim + bk * 64 + tx * 4;
#pragma unroll
        for (int i = 0; i < 4; ++i) {
            int r = ty + i * 16;
            ushort4v o;
            o[0] = tile[tx * 4 + 0][r];
            o[1] = tile[tx * 4 + 1][r];
            o[2] = tile[tx * 4 + 2][r];
            o[3] = tile[tx * 4 + 3][r];
            *(ushort4v*)(dst + (size_t)r * Kdim) = o;
        }
    } else {
        int i = (blockIdx.x - 1024) * 256 + threadIdx.x;  // exactly M*K/8 threads
        const float4* p = (const float4*)x + (size_t)i * 2;
        float4 a = p[0], b = p[1];
        ushort8v o;
        o[0] = f2bf(a.x); o[1] = f2bf(a.y); o[2] = f2bf(a.z); o[3] = f2bf(a.w);
        o[4] = f2bf(b.x); o[5] = f2bf(b.y); o[6] = f2bf(b.z); o[7] = f2bf(b.w);
        *((ushort8v*)xb + i) = o;
    }
}

// ---------------- pass 2: 256x256 GEMM, 1 barrier/K-tile ----------------
// LDS 128 KiB: [dbuf][A/B][half][128 rows x 64 k] bf16 (strides 65536/32768/16384).
// Panel row r -> half (r>>6)&1, rowInHalf (r&63)+(r>>7)*64 (bit-6 split).
// 3-bit XOR swizzle (validated BANK_CONFLICT=0): phys = L ^ ((L>>3)&0x70).
// Per K-tile: [vmcnt(0); s_barrier]  (tile t staged, prev reads retired)
//             [read B + A q0,q1; stage ALL of t+1 -> other buf]
//             [MM0; refill A q2; MM1; refill A q3; MM2; MM3]   (setprio wrapped)
// Reads are consumed by MFMAs (hw lgkm waits) before the next barrier, so the
// following iter's staging into this buffer is WAR-safe. t+1 loads stay in
// flight across the raw s_barrier (no implicit drain).
__global__ __launch_bounds__(512, 2) void gemm_kernel(const unsigned short* __restrict__ xb,
                                                      const unsigned short* __restrict__ wT,
                                                      const float* __restrict__ scales,
                                                      const float* __restrict__ bias,
                                                      float* __restrict__ out) {
    extern __shared__ char ldsc[];

    // XCD-bijective swizzle: nwg = 512, 512 % 8 == 0
    int bid = blockIdx.x;
    int swz = (bid & 7) * 64 + (bid >> 3);
    int tile_n = swz & 15;   // fast: neighbors share A panel in L2
    int tile_m = swz >> 4;

    int tid = threadIdx.x;
    int wid = tid >> 6, lane = tid & 63;
    int wr = wid >> 2, wc = wid & 3;     // wave -> (128 rows, 64 cols) sub-tile
    int la = lane & 15, lq = lane >> 4;

    // ---- staging source offsets (shorts, rel. to half's base row); dest stays linear ----
    int goffs[2];
#pragma unroll
    for (int i = 0; i < 2; ++i) {
        int d = i * 8192 + wid * 1024 + lane * 16;     // physical byte in half
        int L = d ^ ((d >> 3) & 0x70);                 // logical byte (3-bit involution)
        int rih = L >> 7, cb = L & 127;
        int grow = rih + (rih & 64);                   // undo bit6 interleave
        goffs[i] = grow * Kdim + (cb >> 1);
    }
    const unsigned short* aTile = xb + (size_t)tile_m * 256 * Kdim;
    const unsigned short* bTile = wT + (size_t)tile_n * 256 * Kdim;

    auto ISSUE = [&](int t, int op, int h) {   // one half-tile = 2 x global_load_lds16
        const unsigned short* gb = (op ? bTile : aTile) + (size_t)h * (64 * Kdim) + t * 64;
        char* ld = ldsc + (t & 1) * 65536 + op * 32768 + h * 16384 + wid * 1024;
        GLOAD_LDS16(gb + goffs[0], ld);
        GLOAD_LDS16(gb + goffs[1], ld + 8192);
    };

    // ---- ds_read addressing: row byte + 3-bit-swizzled col byte ----
    int ca0 = (lq * 16) ^ ((la & 7) << 4);   // slot = lq ^ (la&7): conflict-free
    int ca1 = ca0 ^ 64;                      // kk*64 commutes with the XOR (bit 6)
    int arow = (wr * 64 + la) * 128;
    int brow = ((wc >> 1) * 64 + la) * 128;

    floatx4 acc[8][4] = {};
    short8 afX[2][2], afY[2][2], bfr[4][2];

#define RD_A(DST, Q)                                                                       \
    _Pragma("unroll") for (int m2 = 0; m2 < 2; ++m2) {                                     \
        DST[m2][0] = *(const short8*)(abase + ((Q) >> 1) * 16384 + ((Q) & 1) * 4096 +      \
                                      m2 * 2048 + arow + ca0);                             \
        DST[m2][1] = *(const short8*)(abase + ((Q) >> 1) * 16384 + ((Q) & 1) * 4096 +      \
                                      m2 * 2048 + arow + ca1);                             \
    }
#define RD_B()                                                                             \
    _Pragma("unroll") for (int ni = 0; ni < 4; ++ni) {                                     \
        bfr[ni][0] = *(const short8*)(bbase + ni * 2048 + brow + ca0);                     \
        bfr[ni][1] = *(const short8*)(bbase + ni * 2048 + brow + ca1);                     \
    }
#define MM(Q, AF)                                                                          \
    _Pragma("unroll") for (int kk = 0; kk < 2; ++kk)                                       \
    _Pragma("unroll") for (int m2 = 0; m2 < 2; ++m2)                                       \
    _Pragma("unroll") for (int ni = 0; ni < 4; ++ni)                                       \
        acc[(Q)*2 + m2][ni] = __builtin_amdgcn_mfma_f32_16x16x32_bf16(                     \
            AF[m2][kk], bfr[ni][kk], acc[(Q)*2 + m2][ni], 0, 0, 0);

    // ---- prologue: stage tile0 (8 loads in flight) ----
    ISSUE(0, 1, 0); ISSUE(0, 1, 1); ISSUE(0, 0, 0); ISSUE(0, 0, 1);

#pragma unroll 1
    for (int t = 0; t < NT; ++t) {
        const char* abase = ldsc + (t & 1) * 65536;
        const char* bbase = ldsc + (t & 1) * 65536 + 32768 + (wc & 1) * 16384;

        asm volatile("s_waitcnt vmcnt(0)" ::: "memory");   // tile t fully staged
        __builtin_amdgcn_s_barrier();                      // prev-iter reads retired

        RD_B(); RD_A(afX, 0); RD_A(afY, 1);                // 16 ds_reads
        if (t + 1 < NT) {                                  // stage t+1 -> other buf
            ISSUE(t + 1, 1, 0); ISSUE(t + 1, 1, 1);
            ISSUE(t + 1, 0, 0); ISSUE(t + 1, 0, 1);
        }
        __builtin_amdgcn_s_setprio(1);
        MM(0, afX);
        RD_A(afX, 2);                                      // refill under MFMA
        MM(1, afY);
        RD_A(afY, 3);
        MM(2, afX);
        MM(3, afY);
        __builtin_amdgcn_s_setprio(0);
    }

    // ---- epilogue: out = acc * scale[n] + bias[n] ----
    size_t m_base = (size_t)tile_m * 256 + wr * 128;
    int n_base = tile_n * 256 + wc * 64;
#pragma unroll
    for (int ni = 0; ni < 4; ++ni) {
        int col = n_base + ni * 16 + la;
        float s = scales[col], bb2 = bias[col];
#pragma unroll
        for (int mi = 0; mi < 8; ++mi) {
            size_t row0 = m_base + mi * 16 + lq * 4;
#pragma unroll
            for (int v = 0; v < 4; ++v)
                out[(row0 + v) * Ndim + col] = acc[mi][ni][v] * s + bb2;
        }
    }
#undef RD_A
#undef RD_B
#undef MM
}

// ---------------- fallback ----------------
__global__ __launch_bounds__(256) void fallback_kernel(const float* __restrict__ x,
                                                       const float* __restrict__ qw,
                                                       const float* __restrict__ scales,
                                                       const float* __restrict__ bias,
                                                       float* __restrict__ out) {
    size_t idx = (size_t)blockIdx.x * 256 + threadIdx.x;
    size_t m = idx / Ndim, n = idx % Ndim;
    float sum = 0.f;
    for (int k = 0; k < Kdim; ++k) sum += x[m * Kdim + k] * qw[(size_t)k * Ndim + n];
    out[idx] = sum * scales[n] + bias[n];
}

extern "C" void kernel_launch(void* const* d_in, const int* in_sizes, int n_in,
                              void* d_out, int out_size, void* d_ws, size_t ws_size,
                              hipStream_t stream) {
    const float* x = (const float*)d_in[0];
    const float* qw = (const float*)d_in[1];
    const float* scales = (const float*)d_in[2];
    const float* bias = (const float*)d_in[3];
    float* out = (float*)d_out;

    size_t need = (size_t)Mdim * Kdim * 2 + (size_t)Ndim * Kdim * 2;  // 24 MB
    if (ws_size < need) {
        fallback_kernel<<<(Mdim * (size_t)Ndim) / 256, 256, 0, stream>>>(x, qw, scales, bias, out);
        return;
    }

    unsigned short* xb = (unsigned short*)d_ws;
    unsigned short* wT = xb + (size_t)Mdim * Kdim;

    (void)hipFuncSetAttribute((const void*)gemm_kernel,
                              hipFuncAttributeMaxDynamicSharedMemorySize, 131072);

    cvt_kernel<<<1024 + Mdim * Kdim / (8 * 256), 256, 0, stream>>>(x, qw, xb, wT);
    gemm_kernel<<<(Mdim / 256) * (Ndim / 256), 512, 131072, stream>>>(xb, wT, scales, bias, out);
}